// Round 1
// baseline (325.522 us; speedup 1.0000x reference)
//
#include <hip/hip_runtime.h>
#include <math.h>

#define T_DIM 4096
#define TRACE 64
#define CTX 64

// One block per t. Precompute per-t trig (64 ctx values) and decay (64 trace
// values) in LDS, then do the elementwise complex MAD with float4 loads/stores.
// Memory-bound: 268 MB in + 134 MB out ~= 402 MB -> ~64 us at 6.3 TB/s.
__global__ __launch_bounds__(256) void ffm_kernel(
    const float* __restrict__ state_re,
    const float* __restrict__ state_im,
    const float* __restrict__ x_re,
    const float* __restrict__ x_im,
    const float* __restrict__ a,
    const float* __restrict__ b,
    const int*   __restrict__ ivec,
    const int*   __restrict__ jvec,
    float* __restrict__ out,       // [T, TRACE, CTX, 2] interleaved re/im
    float* __restrict__ out_cnt)   // [T] (j+i) stored as float values
{
    const int t   = blockIdx.x;
    const int tid = threadIdx.x;
    const float tf = (float)jvec[t];

    __shared__ float s_cos[CTX];
    __shared__ float s_sin[CTX];
    __shared__ float s_dec[TRACE];

    if (tid < CTX) {
        float theta = b[tid] * tf;
        float s, c;
        sincosf(theta, &s, &c);      // accurate: only 64 per block
        s_cos[tid] = c;
        s_sin[tid] = s;
    } else if (tid < CTX + TRACE) {
        int tr = tid - CTX;
        s_dec[tr] = expf(-fabsf(a[tr]) * tf);
    }
    if (tid == 0) {
        out_cnt[t] = (float)(jvec[t] + ivec[t]);
    }
    __syncthreads();

    const size_t base = (size_t)t * (TRACE * CTX);
    const float4* sre = (const float4*)(state_re + base);
    const float4* sim = (const float4*)(state_im + base);
    const float4* xre = (const float4*)(x_re + base);
    const float4* xim = (const float4*)(x_im + base);
    float4* o = (float4*)(out + base * 2);

    // 4096 elements per t = 1024 float4 groups; 256 threads -> 4 groups each.
    #pragma unroll
    for (int k = 0; k < 4; ++k) {
        const int g  = tid + k * 256;   // float4 group index, 0..1023
        const int e  = g * 4;           // element index within [TRACE*CTX]
        const int tr = e >> 6;          // all 4 elems share trace row (CTX=64)
        const int c0 = e & 63;

        const float dec = s_dec[tr];
        const float4 vre = sre[g];
        const float4 vim = sim[g];
        const float4 vxr = xre[g];
        const float4 vxi = xim[g];

        const float gr0 = dec * s_cos[c0 + 0], gi0 = dec * s_sin[c0 + 0];
        const float gr1 = dec * s_cos[c0 + 1], gi1 = dec * s_sin[c0 + 1];
        const float gr2 = dec * s_cos[c0 + 2], gi2 = dec * s_sin[c0 + 2];
        const float gr3 = dec * s_cos[c0 + 3], gi3 = dec * s_sin[c0 + 3];

        float4 o0, o1;
        // elems 0,1 -> o0 ; elems 2,3 -> o1 (re,im interleaved)
        o0.x = fmaf(vre.x, gr0, fmaf(-vim.x, gi0, vxr.x));
        o0.y = fmaf(vre.x, gi0, fmaf( vim.x, gr0, vxi.x));
        o0.z = fmaf(vre.y, gr1, fmaf(-vim.y, gi1, vxr.y));
        o0.w = fmaf(vre.y, gi1, fmaf( vim.y, gr1, vxi.y));
        o1.x = fmaf(vre.z, gr2, fmaf(-vim.z, gi2, vxr.z));
        o1.y = fmaf(vre.z, gi2, fmaf( vim.z, gr2, vxi.z));
        o1.z = fmaf(vre.w, gr3, fmaf(-vim.w, gi3, vxr.w));
        o1.w = fmaf(vre.w, gi3, fmaf( vim.w, gr3, vxi.w));

        o[2 * g + 0] = o0;
        o[2 * g + 1] = o1;
    }
}

extern "C" void kernel_launch(void* const* d_in, const int* in_sizes, int n_in,
                              void* d_out, int out_size, void* d_ws, size_t ws_size,
                              hipStream_t stream) {
    const float* state_re = (const float*)d_in[0];
    const float* state_im = (const float*)d_in[1];
    const float* x_re     = (const float*)d_in[2];
    const float* x_im     = (const float*)d_in[3];
    const float* a        = (const float*)d_in[4];
    const float* b        = (const float*)d_in[5];
    const int*   iv       = (const int*)d_in[6];
    const int*   jv       = (const int*)d_in[7];

    float* out     = (float*)d_out;
    float* out_cnt = out + (size_t)T_DIM * TRACE * CTX * 2;

    ffm_kernel<<<T_DIM, 256, 0, stream>>>(state_re, state_im, x_re, x_im,
                                          a, b, iv, jv, out, out_cnt);
}